// Round 1
// 699.393 us; speedup vs baseline: 1.0625x; 1.0625x over previous
//
#include <hip/hip_runtime.h>
#include <hip/hip_bf16.h>

#define N1 131072
#define E1 2097152
#define N2 2368
#define E2 37888
#define NROIS 148
#define BSZ 16
#define HID 64
#define INCH 128
#define NSEG (BSZ*NROIS)      /* 2368 */
#define SDIM (NROIS*HID)      /* 9472 */
#define CLS 1000
#define OCH 2

#define KT1 74                /* k tiles for k_cls */
#define KCC 128               /* k per tile (74*128 = 9472) */
#define CT1 4                 /* col tiles of 256 */

#define NB1 512               /* dst buckets for graph-1 partition */
#define BLK1 512              /* partition blocks */
#define EPB (E1/BLK1)         /* 4096 edges per block */
#define NPB (N1/NB1)          /* 256 nodes per bucket */

__device__ __forceinline__ float bf2f(unsigned short u) {
    union { unsigned int i; float f; } v; v.i = ((unsigned int)u) << 16; return v.f;
}
__device__ __forceinline__ unsigned short f2bf(float f) {
    union { float f; unsigned int i; } v; v.f = f;
    unsigned int r = v.i + 0x7FFF + ((v.i >> 16) & 1);   // round-to-nearest-even
    return (unsigned short)(r >> 16);
}

// ---------------- generic small-graph CSR build ----------------

__global__ void k_hist_dst(int* __restrict__ cnt, const int* __restrict__ dst, int E) {
    int e = blockIdx.x * 256 + threadIdx.x;
    if (e < E) atomicAdd(&cnt[dst[e]], 1);
}

__global__ void k_hist_seg(int* __restrict__ cnt, const int* __restrict__ batch,
                           const int* __restrict__ label, int n) {
    int i = blockIdx.x * 256 + threadIdx.x;
    if (i < n) atomicAdd(&cnt[batch[i] * NROIS + label[i]], 1);
}

// multi-block exclusive scan
__global__ void k_scan1(const int* __restrict__ in, int* __restrict__ out,
                        int* __restrict__ part, int n) {
    __shared__ int sh[256];
    int t = threadIdx.x;
    int i0 = blockIdx.x * 1024 + t * 4;
    int v0 = (i0     < n) ? in[i0]     : 0;
    int v1 = (i0 + 1 < n) ? in[i0 + 1] : 0;
    int v2 = (i0 + 2 < n) ? in[i0 + 2] : 0;
    int v3 = (i0 + 3 < n) ? in[i0 + 3] : 0;
    int tot = v0 + v1 + v2 + v3;
    sh[t] = tot; __syncthreads();
    for (int off = 1; off < 256; off <<= 1) {
        int x = 0; if (t >= off) x = sh[t - off];
        __syncthreads();
        if (t >= off) sh[t] += x;
        __syncthreads();
    }
    int excl = sh[t] - tot;
    if (t == 255) part[blockIdx.x] = sh[255];
    if (i0     < n) out[i0]     = excl;
    if (i0 + 1 < n) out[i0 + 1] = excl + v0;
    if (i0 + 2 < n) out[i0 + 2] = excl + v0 + v1;
    if (i0 + 3 < n) out[i0 + 3] = excl + v0 + v1 + v2;
}

__global__ void k_scan2(int* __restrict__ part, int cnt) {
    __shared__ int sh[256];
    int t = threadIdx.x;
    int v = (t < cnt) ? part[t] : 0;
    sh[t] = v; __syncthreads();
    for (int off = 1; off < 256; off <<= 1) {
        int x = 0; if (t >= off) x = sh[t - off];
        __syncthreads();
        if (t >= off) sh[t] += x;
        __syncthreads();
    }
    if (t < cnt) part[t] = sh[t] - v;
}

__global__ void k_scan3(int* __restrict__ out, const int* __restrict__ part, int n, int total) {
    int i = blockIdx.x * 256 + threadIdx.x;
    if (i < n) out[i] += part[i >> 10];
    if (i == 0) out[n] = total;
}

// single-block exclusive scan for small arrays; writes sentinel out[n].
// out2 (optional) gets a second copy of the scan (replaces a D2D memcpy dispatch);
// out2 may alias `in` (element i is read before it is written within its chunk).
__global__ void k_scan_one(const int* __restrict__ in, int* __restrict__ out,
                           int* __restrict__ out2, int n) {
    __shared__ int sh[256];
    __shared__ int carry;
    int t = threadIdx.x;
    if (t == 0) carry = 0;
    __syncthreads();
    for (int base = 0; base < n; base += 256) {
        int i = base + t;
        int v = (i < n) ? in[i] : 0;
        sh[t] = v; __syncthreads();
        for (int off = 1; off < 256; off <<= 1) {
            int x = 0; if (t >= off) x = sh[t - off];
            __syncthreads();
            if (t >= off) sh[t] += x;
            __syncthreads();
        }
        if (i < n) {
            int e = carry + sh[t] - v;
            out[i] = e;
            if (out2) out2[i] = e;
        }
        __syncthreads();
        if (t == 255) carry += sh[255];
        __syncthreads();
    }
    if (t == 0) out[n] = carry;
}

__global__ void k_fill_edges(int2* __restrict__ edges, int* __restrict__ off,
                             const int* __restrict__ src, const int* __restrict__ dst,
                             const float* __restrict__ ew, int E) {
    int e = blockIdx.x * 256 + threadIdx.x;
    if (e >= E) return;
    int pos = atomicAdd(&off[dst[e]], 1);
    edges[pos] = make_int2(src[e], __float_as_int(ew[e]));
}

__global__ void k_fill_seg(int* __restrict__ nodeid, int* __restrict__ off,
                           const int* __restrict__ batch, const int* __restrict__ label, int n) {
    int i = blockIdx.x * 256 + threadIdx.x;
    if (i >= n) return;
    int pos = atomicAdd(&off[batch[i] * NROIS + label[i]], 1);
    nodeid[pos] = i;
}

__global__ void k_deg_dinv(float* __restrict__ dinv, const int* __restrict__ row,
                           const int2* __restrict__ edges, int n) {
    int d = blockIdx.x * 256 + threadIdx.x;
    if (d >= n) return;
    int a = row[d], b = row[d + 1];
    float s = 1.0f;
    for (int i = a; i < b; i++) s += __int_as_float(edges[i].y);
    dinv[d] = rsqrtf(s);
}

__global__ void k_scale(int2* __restrict__ edges, const int* __restrict__ row,
                        const float* __restrict__ dinv, int n) {
    int d = blockIdx.x * 256 + threadIdx.x;
    if (d >= n) return;
    int a = row[d], b = row[d + 1];
    float dd = dinv[d];
    for (int i = a; i < b; i++) {
        int2 e = edges[i];
        edges[i].y = __float_as_int(dinv[e.x] * __int_as_float(e.y) * dd);
    }
}

// ---------------- graph-1 radix-partition CSR build ----------------

__global__ __launch_bounds__(256) void k_p1(int* __restrict__ bh, const int* __restrict__ dst) {
    __shared__ int cnt[NB1];
    int t = threadIdx.x, blk = blockIdx.x;
    for (int i = t; i < NB1; i += 256) cnt[i] = 0;
    __syncthreads();
    int base = blk * EPB;
    for (int i = t; i < EPB; i += 256) atomicAdd(&cnt[dst[base + i] >> 8], 1);
    __syncthreads();
    for (int b = t; b < NB1; b += 256) bh[b * BLK1 + blk] = cnt[b];   // bucket-major
}

// pack = src (17 bits) | dst_local (8 bits) << 17
__global__ __launch_bounds__(256) void k_p2(int2* __restrict__ tmp, const int* __restrict__ obh,
                                            const int* __restrict__ src,
                                            const int* __restrict__ dst,
                                            const float* __restrict__ ew) {
    __shared__ int cur[NB1];
    int t = threadIdx.x, blk = blockIdx.x;
    for (int b = t; b < NB1; b += 256) cur[b] = obh[b * BLK1 + blk];
    __syncthreads();
    int base = blk * EPB;
    for (int i = t; i < EPB; i += 256) {
        int e = base + i;
        int d = dst[e];
        int pos = atomicAdd(&cur[d >> 8], 1);
        tmp[pos] = make_int2(src[e] | ((d & 255) << 17), __float_as_int(ew[e]));
    }
}

__global__ __launch_bounds__(256) void k_p3a(int* __restrict__ deg, float* __restrict__ dinv,
                                             const int2* __restrict__ tmp,
                                             const int* __restrict__ obh) {
    __shared__ int h[NPB];
    __shared__ float ws[NPB];
    int t = threadIdx.x, b = blockIdx.x;
    for (int i = t; i < NPB; i += 256) { h[i] = 0; ws[i] = 0.f; }
    __syncthreads();
    int a  = obh[b * BLK1];
    int e_ = (b == NB1 - 1) ? E1 : obh[(b + 1) * BLK1];
    for (int i = a + t; i < e_; i += 256) {
        int2 ed = tmp[i];
        int dl = (ed.x >> 17) & 255;
        atomicAdd(&h[dl], 1);
        atomicAdd(&ws[dl], __int_as_float(ed.y));
    }
    __syncthreads();
    for (int i = t; i < NPB; i += 256) {
        deg[b * NPB + i] = h[i];
        dinv[b * NPB + i] = rsqrtf(1.f + ws[i]);
    }
}

__global__ __launch_bounds__(256) void k_p3b(int2* __restrict__ edges,
                                             const int2* __restrict__ tmp,
                                             const int* __restrict__ obh,
                                             const int* __restrict__ row,
                                             const float* __restrict__ dinv) {
    __shared__ int cur[NPB];
    __shared__ float dvl[NPB];
    int t = threadIdx.x, b = blockIdx.x;
    int n0 = b * NPB;
    for (int i = t; i < NPB; i += 256) {
        cur[i] = row[n0 + i];
        dvl[i] = dinv[n0 + i];
    }
    __syncthreads();
    int a  = obh[b * BLK1];
    int e_ = (b == NB1 - 1) ? E1 : obh[(b + 1) * BLK1];
    for (int i = a + t; i < e_; i += 256) {
        int2 ed = tmp[i];
        int dl = (ed.x >> 17) & 255;
        int s = ed.x & 0x1FFFF;
        int pos = atomicAdd(&cur[dl], 1);
        float w = dinv[s] * __int_as_float(ed.y) * dvl[dl];
        edges[pos] = make_int2(s, __float_as_int(w));
    }
}

// ---------------- dense ops ----------------

// out_bf16[n][64] = x[n][K] @ W[K][64]. Block: 256 rows x 64 cols; tile 8x8.
// Output stored as bf16 (halves the conv gather volume).
template <int K>
__global__ __launch_bounds__(256) void k_gemm(unsigned short* __restrict__ out,
                                              const float* __restrict__ x,
                                              const float* __restrict__ W, int n) {
    __shared__ float Wl[32 * 64];       // [kk][col]
    __shared__ float xs[256 * 37];      // [r][kk], stride 37
    int tid = threadIdx.x;
    int row0 = blockIdx.x * 256;
    int r0 = (tid >> 3) * 8;
    int c0 = (tid & 7) * 8;
    float acc[8][8];
#pragma unroll
    for (int i = 0; i < 8; i++)
#pragma unroll
        for (int j = 0; j < 8; j++) acc[i][j] = 0.f;

    for (int k0 = 0; k0 < K; k0 += 32) {
        __syncthreads();
        {
            const float4* W4 = (const float4*)(W + k0 * 64);
            float4* Wl4 = (float4*)Wl;
#pragma unroll
            for (int i = 0; i < 2; i++) Wl4[tid + i * 256] = W4[tid + i * 256];
        }
#pragma unroll
        for (int i = 0; i < 8; i++) {
            int idx = tid + i * 256;
            int r = idx >> 3, kq = idx & 7;
            float4 v = make_float4(0.f, 0.f, 0.f, 0.f);
            if (row0 + r < n)
                v = *(const float4*)(x + (size_t)(row0 + r) * K + k0 + kq * 4);
            xs[r * 37 + kq * 4 + 0] = v.x;
            xs[r * 37 + kq * 4 + 1] = v.y;
            xs[r * 37 + kq * 4 + 2] = v.z;
            xs[r * 37 + kq * 4 + 3] = v.w;
        }
        __syncthreads();
#pragma unroll 2
        for (int kk = 0; kk < 32; kk++) {
            float4 wlo = *(const float4*)(&Wl[kk * 64 + c0]);
            float4 whi = *(const float4*)(&Wl[kk * 64 + c0 + 4]);
            float xf[8];
#pragma unroll
            for (int i = 0; i < 8; i++) xf[i] = xs[(r0 + i) * 37 + kk];
#pragma unroll
            for (int i = 0; i < 8; i++) {
                acc[i][0] += xf[i] * wlo.x; acc[i][1] += xf[i] * wlo.y;
                acc[i][2] += xf[i] * wlo.z; acc[i][3] += xf[i] * wlo.w;
                acc[i][4] += xf[i] * whi.x; acc[i][5] += xf[i] * whi.y;
                acc[i][6] += xf[i] * whi.z; acc[i][7] += xf[i] * whi.w;
            }
        }
    }
#pragma unroll
    for (int i = 0; i < 8; i++) {
        int row = row0 + r0 + i;
        if (row < n) {
            uint4 o;
            o.x = (unsigned int)f2bf(acc[i][0]) | ((unsigned int)f2bf(acc[i][1]) << 16);
            o.y = (unsigned int)f2bf(acc[i][2]) | ((unsigned int)f2bf(acc[i][3]) << 16);
            o.z = (unsigned int)f2bf(acc[i][4]) | ((unsigned int)f2bf(acc[i][5]) << 16);
            o.w = (unsigned int)f2bf(acc[i][6]) | ((unsigned int)f2bf(acc[i][7]) << 16);
            *(uint4*)(out + (size_t)row * 64 + c0) = o;
        }
    }
}

// fused GCN aggregate: wave per dst node, reorganized as 4 edge-slots x 16 lanes.
// Each lane loads uint2 (4 bf16 features, 8 B) -> one wave-load gathers 4 full
// h-rows (512 B) vs 1 row before: ~3 wave-instrs/edge instead of ~8, and 4x the
// bytes in flight. Tail edges are zero-weight-padded (harmless gather of row 0).
__global__ __launch_bounds__(256) void k_conv(float* __restrict__ out,
                                              const unsigned short* __restrict__ h,
                                              const int2* __restrict__ edges,
                                              const int* __restrict__ row,
                                              const float* __restrict__ dinv,
                                              const float* __restrict__ bias, int n) {
    int d = blockIdx.x * 4 + (threadIdx.x >> 6);
    if (d >= n) return;
    int lane = threadIdx.x & 63;
    int g = lane >> 4;            // edge slot 0..3
    int f4 = lane & 15;           // feature quad: features f4*4 .. f4*4+3
    int a = row[d], b = row[d + 1];
    float acc0[4] = {0.f, 0.f, 0.f, 0.f};
    float acc1[4] = {0.f, 0.f, 0.f, 0.f};
    for (int base = a; base < b; base += 64) {
        int m = b - base; if (m > 64) m = 64;
        int sv = 0, wv = 0;       // zero-pad: w=0 kills invalid-slot contributions
        if (base + lane < b) { int2 e = edges[base + lane]; sv = e.x; wv = e.y; }
        for (int j = 0; j < m; j += 8) {
            int   s0 = __shfl(sv, j + g);
            float w0 = __int_as_float(__shfl(wv, j + g));
            int   s1 = __shfl(sv, j + 4 + g);
            float w1 = __int_as_float(__shfl(wv, j + 4 + g));
            uint2 h0 = *(const uint2*)(h + (size_t)s0 * HID + (f4 << 2));
            uint2 h1 = *(const uint2*)(h + (size_t)s1 * HID + (f4 << 2));
            acc0[0] += __uint_as_float(h0.x << 16)          * w0;
            acc0[1] += __uint_as_float(h0.x & 0xFFFF0000u)  * w0;
            acc0[2] += __uint_as_float(h0.y << 16)          * w0;
            acc0[3] += __uint_as_float(h0.y & 0xFFFF0000u)  * w0;
            acc1[0] += __uint_as_float(h1.x << 16)          * w1;
            acc1[1] += __uint_as_float(h1.x & 0xFFFF0000u)  * w1;
            acc1[2] += __uint_as_float(h1.y << 16)          * w1;
            acc1[3] += __uint_as_float(h1.y & 0xFFFF0000u)  * w1;
        }
    }
    // fold the 4 edge-slots: lanes {f4, f4+16, f4+32, f4+48} hold partials
    float r0 = acc0[0] + acc1[0];
    float r1 = acc0[1] + acc1[1];
    float r2 = acc0[2] + acc1[2];
    float r3 = acc0[3] + acc1[3];
    r0 += __shfl_xor(r0, 16); r0 += __shfl_xor(r0, 32);
    r1 += __shfl_xor(r1, 16); r1 += __shfl_xor(r1, 32);
    r2 += __shfl_xor(r2, 16); r2 += __shfl_xor(r2, 32);
    r3 += __shfl_xor(r3, 16); r3 += __shfl_xor(r3, 32);
    if (g == 0) {
        float di = dinv[d];
        float sl = di * di;
        uint2 hd = *(const uint2*)(h + (size_t)d * HID + (f4 << 2));
        float4 bb = *(const float4*)(bias + (f4 << 2));
        float v0 = r0 + __uint_as_float(hd.x << 16)         * sl + bb.x;
        float v1 = r1 + __uint_as_float(hd.x & 0xFFFF0000u) * sl + bb.y;
        float v2 = r2 + __uint_as_float(hd.y << 16)         * sl + bb.z;
        float v3 = r3 + __uint_as_float(hd.y & 0xFFFF0000u) * sl + bb.w;
        float4 o;
        o.x = v0 > 0.f ? v0 : 0.f;
        o.y = v1 > 0.f ? v1 : 0.f;
        o.z = v2 > 0.f ? v2 : 0.f;
        o.w = v3 > 0.f ? v3 : 0.f;
        *(float4*)(out + (size_t)d * HID + (f4 << 2)) = o;
    }
}

// segment-mean pool: wave per segment, 4 node-slots x 16 lanes, float4 gathers
// (one wave-load = 4 full fp32 rows). Same reshape as k_conv.
__global__ __launch_bounds__(256) void k_pool(float* __restrict__ emb, float* __restrict__ esum,
                                              const float* __restrict__ embo,
                                              const float* __restrict__ h,
                                              const int* __restrict__ nodeid,
                                              const int* __restrict__ segrow) {
    int s = blockIdx.x * 4 + (threadIdx.x >> 6);
    if (s >= NSEG) return;
    int lane = threadIdx.x & 63;
    int g = lane >> 4;
    int f4 = lane & 15;
    int a = segrow[s], b = segrow[s + 1];
    float acc0[4] = {0.f, 0.f, 0.f, 0.f};
    float acc1[4] = {0.f, 0.f, 0.f, 0.f};
    for (int base = a; base < b; base += 64) {
        int m = b - base; if (m > 64) m = 64;
        int nid = -1;
        if (base + lane < b) nid = nodeid[base + lane];
        for (int j = 0; j < m; j += 8) {
            int n0 = __shfl(nid, j + g);
            int n1 = __shfl(nid, j + 4 + g);
            if (n0 >= 0) {
                float4 v = *(const float4*)(h + (size_t)n0 * HID + (f4 << 2));
                acc0[0] += v.x; acc0[1] += v.y; acc0[2] += v.z; acc0[3] += v.w;
            }
            if (n1 >= 0) {
                float4 v = *(const float4*)(h + (size_t)n1 * HID + (f4 << 2));
                acc1[0] += v.x; acc1[1] += v.y; acc1[2] += v.z; acc1[3] += v.w;
            }
        }
    }
    float r0 = acc0[0] + acc1[0];
    float r1 = acc0[1] + acc1[1];
    float r2 = acc0[2] + acc1[2];
    float r3 = acc0[3] + acc1[3];
    r0 += __shfl_xor(r0, 16); r0 += __shfl_xor(r0, 32);
    r1 += __shfl_xor(r1, 16); r1 += __shfl_xor(r1, 32);
    r2 += __shfl_xor(r2, 16); r2 += __shfl_xor(r2, 32);
    r3 += __shfl_xor(r3, 16); r3 += __shfl_xor(r3, 32);
    if (g == 0) {
        float inv = 1.0f / fmaxf((float)(b - a), 1.0f);
        float4 mv = make_float4(r0 * inv, r1 * inv, r2 * inv, r3 * inv);
        *(float4*)(emb + (size_t)s * HID + (f4 << 2)) = mv;
        if (esum) {
            float4 eo = *(const float4*)(embo + (size_t)s * HID + (f4 << 2));
            float4 sv = make_float4(mv.x + eo.x, mv.y + eo.y, mv.z + eo.z, mv.w + eo.w);
            *(float4*)(esum + (size_t)s * HID + (f4 << 2)) = sv;
        }
    }
}

// ---------------- classifier ----------------

__global__ __launch_bounds__(256) void k_cls(float* __restrict__ part_,
                                             const float* __restrict__ s,
                                             const float* __restrict__ Wm1) {
    __shared__ float sl[KCC * 16];      // [kk][b]
    int tid = threadIdx.x;
    int kt = blockIdx.x >> 2, ct = blockIdx.x & 3;
    int k0 = kt * KCC;
    for (int i = tid; i < KCC * 16; i += 256) {
        int kk = i & (KCC - 1), b = i >> 7;        // coalesced over kk
        sl[kk * 16 + b] = s[b * SDIM + k0 + kk];
    }
    __syncthreads();
    int c = ct * 256 + tid;
    bool active = c < CLS;
    float acc[16];
#pragma unroll
    for (int b = 0; b < 16; b++) acc[b] = 0.f;
    const float* wp = Wm1 + (size_t)k0 * CLS + c;
#pragma unroll 2
    for (int kk = 0; kk < KCC; kk++) {
        float w = active ? wp[(size_t)kk * CLS] : 0.f;
        float4 s0 = *(const float4*)(&sl[kk * 16 + 0]);
        float4 s1 = *(const float4*)(&sl[kk * 16 + 4]);
        float4 s2 = *(const float4*)(&sl[kk * 16 + 8]);
        float4 s3 = *(const float4*)(&sl[kk * 16 + 12]);
        acc[0]  += s0.x * w; acc[1]  += s0.y * w; acc[2]  += s0.z * w; acc[3]  += s0.w * w;
        acc[4]  += s1.x * w; acc[5]  += s1.y * w; acc[6]  += s1.z * w; acc[7]  += s1.w * w;
        acc[8]  += s2.x * w; acc[9]  += s2.y * w; acc[10] += s2.z * w; acc[11] += s2.w * w;
        acc[12] += s3.x * w; acc[13] += s3.y * w; acc[14] += s3.z * w; acc[15] += s3.w * w;
    }
    float* pp = part_ + (size_t)(kt * CT1 + ct) * 16 * 256;
#pragma unroll
    for (int b = 0; b < 16; b++) pp[b * 256 + tid] = acc[b];
}

// reduce partials + BatchNorm + LeakyReLU in one pass
__global__ void k_credbn(float* __restrict__ hact, const float* __restrict__ part_,
                         const float* __restrict__ bm1, const float* __restrict__ gamma,
                         const float* __restrict__ beta, const float* __restrict__ mean,
                         const float* __restrict__ var) {
    int idx = blockIdx.x * 256 + threadIdx.x;
    if (idx >= BSZ * CLS) return;
    int b = idx / CLS, c = idx % CLS;
    int ct = c >> 8, cl = c & 255;
    float sum = 0.f;
#pragma unroll 2
    for (int kt = 0; kt < KT1; kt++)
        sum += part_[((size_t)(kt * CT1 + ct) * 16 + b) * 256 + cl];
    float t = sum + bm1[c];
    t = gamma[c] * (t - mean[c]) * rsqrtf(var[c] + 1e-5f) + beta[c];
    hact[idx] = t > 0.f ? t : 0.01f * t;
}

__global__ void k_out(float* __restrict__ outp, const float* __restrict__ hact,
                      const float* __restrict__ Wm2, const float* __restrict__ bm2) {
    int tid = threadIdx.x;              // one block of 256
    int oi = tid >> 3, part = tid & 7;  // 32 outputs x 8 partials
    int b = oi >> 1, o = oi & 1;
    float acc = (part == 0) ? bm2[o] : 0.f;
    for (int k = part; k < CLS; k += 8) acc += hact[b * CLS + k] * Wm2[k * OCH + o];
    unsafeAtomicAdd(&outp[b * OCH + o], acc);
}

extern "C" void kernel_launch(void* const* d_in, const int* in_sizes, int n_in,
                              void* d_out, int out_size, void* d_ws, size_t ws_size,
                              hipStream_t stream) {
    const float* x1  = (const float*)d_in[0];
    const int*   nl  = (const int*)d_in[1];
    const int*   ei1 = (const int*)d_in[2];
    const float* ew1 = (const float*)d_in[3];
    const int*   ba1 = (const int*)d_in[4];
    const float* x2  = (const float*)d_in[5];
    const int*   rl  = (const int*)d_in[6];
    const int*   ei2 = (const int*)d_in[7];
    const float* ew2 = (const float*)d_in[8];
    const int*   ba2 = (const int*)d_in[9];
    const float* W1a = (const float*)d_in[10];
    const float* b1a = (const float*)d_in[11];
    const float* W1b = (const float*)d_in[12];
    const float* b1b = (const float*)d_in[13];
    const float* W2a = (const float*)d_in[14];
    const float* b2a = (const float*)d_in[15];
    const float* W2b = (const float*)d_in[16];
    const float* b2b = (const float*)d_in[17];
    const float* Wm1 = (const float*)d_in[18];
    const float* bm1 = (const float*)d_in[19];
    const float* gam = (const float*)d_in[20];
    const float* bet = (const float*)d_in[21];
    const float* bmn = (const float*)d_in[22];
    const float* bvr = (const float*)d_in[23];
    const float* Wm2 = (const float*)d_in[24];
    const float* bm2 = (const float*)d_in[25];

    float* out  = (float*)d_out;
    float* emb1 = out + 32;               // embedding        (16 x 9472)
    float* emb2 = emb1 + NSEG * HID;      // embedding_roi
    float* esum = emb2 + NSEG * HID;      // embedding + embedding_roi

    // ---- workspace carve ----
    char* p = (char*)d_ws;
    auto carve = [&](size_t nbytes) { char* q = p; p += (nbytes + 255) & ~(size_t)255; return (void*)q; };
    int*            row1    = (int*)   carve((N1 + 1) * 4);
    int2*           edges1  = (int2*)  carve((size_t)E1 * 8);
    float*          dinv1   = (float*) carve(N1 * 4);
    unsigned short* A1b     = (unsigned short*)carve((size_t)N1 * HID * 2);  // bf16 h
    float*          B1      = (float*) carve((size_t)N1 * HID * 4);
    int*            nodeid1 = (int*)   carve(N1 * 4);
    int*            segrow1 = (int*)   carve((NSEG + 1) * 4);
    int*            segoff1 = (int*)   carve(NSEG * 4);
    int*            bh      = (int*)   carve((NB1 * BLK1 + 1) * 4);
    int*            obh     = (int*)   carve((NB1 * BLK1 + 1) * 4);
    int*            deg     = (int*)   carve(N1 * 4);
    int*            row2    = (int*)   carve((N2 + 1) * 4);
    int*            off2    = (int*)   carve(N2 * 4);
    int2*           edges2  = (int2*)  carve((size_t)E2 * 8);
    float*          dinv2   = (float*) carve(N2 * 4);
    unsigned short* A2b     = (unsigned short*)carve((size_t)N2 * HID * 2);
    float*          B2      = (float*) carve((size_t)N2 * HID * 4);
    int*            nodeid2 = (int*)   carve(N2 * 4);
    int*            segrow2 = (int*)   carve((NSEG + 1) * 4);
    int*            segoff2 = (int*)   carve(NSEG * 4);
    int*            part    = (int*)   carve(256 * 4);
    float*          hact    = (float*) carve(BSZ * CLS * 4);
    int2* tmp1 = (int2*)B1;   // 16.8 MB aliases B1 (33.5 MB): CSR build done
                              // before conv1's first B1 write
    float* clsp = B1;         // 4.85 MB partial slabs alias B1: B1 dead after last k_pool

    const int* src1 = ei1;
    const int* dst1 = ei1 + E1;
    const int* src2 = ei2;
    const int* dst2 = ei2 + E2;

    hipMemsetAsync(d_out, 0, (size_t)out_size * sizeof(float), stream);

    // ---------------- graph 2 (ROI graph, small) ----------------
    hipMemsetAsync(off2, 0, N2 * 4, stream);
    k_hist_dst<<<(E2 + 255) / 256, 256, 0, stream>>>(off2, dst2, E2);
    k_scan_one<<<1, 256, 0, stream>>>(off2, row2, off2, N2);   // off2 gets scan copy in-place
    k_fill_edges<<<(E2 + 255) / 256, 256, 0, stream>>>(edges2, off2, src2, dst2, ew2, E2);
    k_deg_dinv<<<(N2 + 255) / 256, 256, 0, stream>>>(dinv2, row2, edges2, N2);
    k_scale<<<(N2 + 255) / 256, 256, 0, stream>>>(edges2, row2, dinv2, N2);

    k_gemm<INCH><<<(N2 + 255) / 256, 256, 0, stream>>>(A2b, x2, W2a, N2);
    k_conv<<<(N2 + 3) / 4, 256, 0, stream>>>(B2, A2b, edges2, row2, dinv2, b2a, N2);
    k_gemm<HID><<<(N2 + 255) / 256, 256, 0, stream>>>(A2b, B2, W2b, N2);
    k_conv<<<(N2 + 3) / 4, 256, 0, stream>>>(B2, A2b, edges2, row2, dinv2, b2b, N2);
    // graph-2 final features now in B2 (fp32)

    hipMemsetAsync(segoff2, 0, NSEG * 4, stream);
    k_hist_seg<<<(N2 + 255) / 256, 256, 0, stream>>>(segoff2, ba2, rl, N2);
    k_scan_one<<<1, 256, 0, stream>>>(segoff2, segrow2, segoff2, NSEG);
    k_fill_seg<<<(N2 + 255) / 256, 256, 0, stream>>>(nodeid2, segoff2, ba2, rl, N2);
    k_pool<<<(NSEG + 3) / 4, 256, 0, stream>>>(emb2, (float*)nullptr, (const float*)nullptr,
                                               B2, nodeid2, segrow2);

    // ---------------- graph 1: radix-partition CSR build ----------------
    k_p1<<<BLK1, 256, 0, stream>>>(bh, dst1);
    k_scan1<<<(NB1 * BLK1 + 1023) / 1024, 256, 0, stream>>>(bh, obh, part, NB1 * BLK1);
    k_scan2<<<1, 256, 0, stream>>>(part, (NB1 * BLK1 + 1023) / 1024);
    k_scan3<<<(NB1 * BLK1 + 255) / 256, 256, 0, stream>>>(obh, part, NB1 * BLK1, E1);
    k_p2<<<BLK1, 256, 0, stream>>>(tmp1, obh, src1, dst1, ew1);
    k_p3a<<<NB1, 256, 0, stream>>>(deg, dinv1, tmp1, obh);
    k_scan1<<<(N1 + 1023) / 1024, 256, 0, stream>>>(deg, row1, part, N1);
    k_scan2<<<1, 256, 0, stream>>>(part, (N1 + 1023) / 1024);
    k_scan3<<<(N1 + 255) / 256, 256, 0, stream>>>(row1, part, N1, E1);
    k_p3b<<<NB1, 256, 0, stream>>>(edges1, tmp1, obh, row1, dinv1);

    // ---------------- graph 1: convs ----------------
    k_gemm<INCH><<<N1 / 256, 256, 0, stream>>>(A1b, x1, W1a, N1);
    k_conv<<<(N1 + 3) / 4, 256, 0, stream>>>(B1, A1b, edges1, row1, dinv1, b1a, N1);
    k_gemm<HID><<<N1 / 256, 256, 0, stream>>>(A1b, B1, W1b, N1);
    k_conv<<<(N1 + 3) / 4, 256, 0, stream>>>(B1, A1b, edges1, row1, dinv1, b1b, N1);

    hipMemsetAsync(segoff1, 0, NSEG * 4, stream);
    k_hist_seg<<<(N1 + 255) / 256, 256, 0, stream>>>(segoff1, ba1, nl, N1);
    k_scan_one<<<1, 256, 0, stream>>>(segoff1, segrow1, segoff1, NSEG);
    k_fill_seg<<<(N1 + 255) / 256, 256, 0, stream>>>(nodeid1, segoff1, ba1, nl, N1);
    k_pool<<<(NSEG + 3) / 4, 256, 0, stream>>>(emb1, esum, emb2, B1, nodeid1, segrow1);
    // B1 dead from here; clsp aliases it

    // ---------------- classifier ----------------
    k_cls<<<KT1 * CT1, 256, 0, stream>>>(clsp, esum, Wm1);
    k_credbn<<<(BSZ * CLS + 255) / 256, 256, 0, stream>>>(hact, clsp, bm1, gam, bet, bmn, bvr);
    k_out<<<1, 256, 0, stream>>>(out, hact, Wm2, bm2);
}

// Round 2
// 612.283 us; speedup vs baseline: 1.2137x; 1.1423x over previous
//
#include <hip/hip_runtime.h>
#include <hip/hip_fp16.h>

#define N1 131072
#define E1 2097152
#define N2 2368
#define E2 37888
#define NROIS 148
#define BSZ 16
#define HID 64
#define INCH 128
#define NSEG (BSZ*NROIS)      /* 2368 */
#define SDIM (NROIS*HID)      /* 9472 */
#define CLS 1000
#define OCH 2

#define KT1 74                /* k tiles for k_cls */
#define KCC 128               /* k per tile (74*128 = 9472) */
#define CT1 4                 /* col tiles of 256 */

#define NB1 512               /* dst buckets for graph-1 partition */
#define BLK1 512              /* partition blocks */
#define EPB (E1/BLK1)         /* 4096 edges per block */
#define NPB (N1/NB1)          /* 256 nodes per bucket */

#define GB1 (N1/256)          /* 512 gemm blocks graph1 */
#define GB2 ((N2+255)/256)    /* 10 gemm blocks graph2 */
#define CB1 ((N1+3)/4)        /* 32768 conv blocks graph1 */
#define CB2 ((N2+3)/4)        /* 592 conv blocks graph2 */
#define PB  ((NSEG+3)/4)      /* 592 pool blocks per graph */

__device__ __forceinline__ unsigned packh2(float a, float b) {
    return (unsigned)__half_as_ushort(__float2half_rn(a)) |
           ((unsigned)__half_as_ushort(__float2half_rn(b)) << 16);
}

// ---------------- generic small-graph CSR build ----------------

__global__ void k_hist_dst(int* __restrict__ cnt, const int* __restrict__ dst, int E) {
    int e = blockIdx.x * 256 + threadIdx.x;
    if (e < E) atomicAdd(&cnt[dst[e]], 1);
}

// fused over both graphs: thread i handles graph-1 item i or graph-2 item i-n1
__global__ void k_hist_seg2(int* __restrict__ c1, const int* __restrict__ b1,
                            const int* __restrict__ l1, int n1_,
                            int* __restrict__ c2, const int* __restrict__ b2,
                            const int* __restrict__ l2, int n2_) {
    int i = blockIdx.x * 256 + threadIdx.x;
    if (i < n1_) { atomicAdd(&c1[b1[i] * NROIS + l1[i]], 1); return; }
    int j = i - n1_;
    if (j < n2_) atomicAdd(&c2[b2[j] * NROIS + l2[j]], 1);
}

// multi-block exclusive scan
__global__ void k_scan1(const int* __restrict__ in, int* __restrict__ out,
                        int* __restrict__ part, int n) {
    __shared__ int sh[256];
    int t = threadIdx.x;
    int i0 = blockIdx.x * 1024 + t * 4;
    int v0 = (i0     < n) ? in[i0]     : 0;
    int v1 = (i0 + 1 < n) ? in[i0 + 1] : 0;
    int v2 = (i0 + 2 < n) ? in[i0 + 2] : 0;
    int v3 = (i0 + 3 < n) ? in[i0 + 3] : 0;
    int tot = v0 + v1 + v2 + v3;
    sh[t] = tot; __syncthreads();
    for (int off = 1; off < 256; off <<= 1) {
        int x = 0; if (t >= off) x = sh[t - off];
        __syncthreads();
        if (t >= off) sh[t] += x;
        __syncthreads();
    }
    int excl = sh[t] - tot;
    if (t == 255) part[blockIdx.x] = sh[255];
    if (i0     < n) out[i0]     = excl;
    if (i0 + 1 < n) out[i0 + 1] = excl + v0;
    if (i0 + 2 < n) out[i0 + 2] = excl + v0 + v1;
    if (i0 + 3 < n) out[i0 + 3] = excl + v0 + v1 + v2;
}

__global__ void k_scan2(int* __restrict__ part, int cnt) {
    __shared__ int sh[256];
    int t = threadIdx.x;
    int v = (t < cnt) ? part[t] : 0;
    sh[t] = v; __syncthreads();
    for (int off = 1; off < 256; off <<= 1) {
        int x = 0; if (t >= off) x = sh[t - off];
        __syncthreads();
        if (t >= off) sh[t] += x;
        __syncthreads();
    }
    if (t < cnt) part[t] = sh[t] - v;
}

__global__ void k_scan3(int* __restrict__ out, const int* __restrict__ part, int n, int total) {
    int i = blockIdx.x * 256 + threadIdx.x;
    if (i < n) out[i] += part[i >> 10];
    if (i == 0) out[n] = total;
}

// single-block exclusive scan; block 0 scans set A, block 1 (if in1 != null) set B.
// out2 gets a second copy of the scan (replaces a D2D memcpy); may alias `in`.
__global__ void k_scan_one(const int* __restrict__ in0, int* __restrict__ out0,
                           int* __restrict__ oo0, int n0,
                           const int* __restrict__ in1, int* __restrict__ out1,
                           int* __restrict__ oo1, int n1_) {
    __shared__ int sh[256];
    __shared__ int carry;
    const int* in; int* out; int* oo; int n;
    if (blockIdx.x == 0) { in = in0; out = out0; oo = oo0; n = n0; }
    else { if (!in1) return; in = in1; out = out1; oo = oo1; n = n1_; }
    int t = threadIdx.x;
    if (t == 0) carry = 0;
    __syncthreads();
    for (int base = 0; base < n; base += 256) {
        int i = base + t;
        int v = (i < n) ? in[i] : 0;
        sh[t] = v; __syncthreads();
        for (int off = 1; off < 256; off <<= 1) {
            int x = 0; if (t >= off) x = sh[t - off];
            __syncthreads();
            if (t >= off) sh[t] += x;
            __syncthreads();
        }
        if (i < n) {
            int e = carry + sh[t] - v;
            out[i] = e;
            if (oo) oo[i] = e;
        }
        __syncthreads();
        if (t == 255) carry += sh[255];
        __syncthreads();
    }
    if (t == 0) out[n] = carry;
}

__global__ void k_fill_edges(int2* __restrict__ edges, int* __restrict__ off,
                             const int* __restrict__ src, const int* __restrict__ dst,
                             const float* __restrict__ ew, int E) {
    int e = blockIdx.x * 256 + threadIdx.x;
    if (e >= E) return;
    int pos = atomicAdd(&off[dst[e]], 1);
    edges[pos] = make_int2(src[e], __float_as_int(ew[e]));
}

__global__ void k_fill_seg2(int* __restrict__ id1, int* __restrict__ o1,
                            const int* __restrict__ b1, const int* __restrict__ l1, int n1_,
                            int* __restrict__ id2, int* __restrict__ o2,
                            const int* __restrict__ b2, const int* __restrict__ l2, int n2_) {
    int i = blockIdx.x * 256 + threadIdx.x;
    if (i < n1_) {
        int pos = atomicAdd(&o1[b1[i] * NROIS + l1[i]], 1);
        id1[pos] = i;
        return;
    }
    int j = i - n1_;
    if (j < n2_) {
        int pos = atomicAdd(&o2[b2[j] * NROIS + l2[j]], 1);
        id2[pos] = j;
    }
}

__global__ void k_deg_dinv(float* __restrict__ dinv, const int* __restrict__ row,
                           const int2* __restrict__ edges, int n) {
    int d = blockIdx.x * 256 + threadIdx.x;
    if (d >= n) return;
    int a = row[d], b = row[d + 1];
    float s = 1.0f;
    for (int i = a; i < b; i++) s += __int_as_float(edges[i].y);
    dinv[d] = rsqrtf(s);
}

__global__ void k_scale(int2* __restrict__ edges, const int* __restrict__ row,
                        const float* __restrict__ dinv, int n) {
    int d = blockIdx.x * 256 + threadIdx.x;
    if (d >= n) return;
    int a = row[d], b = row[d + 1];
    float dd = dinv[d];
    for (int i = a; i < b; i++) {
        int2 e = edges[i];
        edges[i].y = __float_as_int(dinv[e.x] * __int_as_float(e.y) * dd);
    }
}

// ---------------- graph-1 radix-partition CSR build ----------------

__global__ __launch_bounds__(256) void k_p1(int* __restrict__ bh, const int* __restrict__ dst) {
    __shared__ int cnt[NB1];
    int t = threadIdx.x, blk = blockIdx.x;
    for (int i = t; i < NB1; i += 256) cnt[i] = 0;
    __syncthreads();
    int base = blk * EPB;
    for (int i = t; i < EPB; i += 256) atomicAdd(&cnt[dst[base + i] >> 8], 1);
    __syncthreads();
    for (int b = t; b < NB1; b += 256) bh[b * BLK1 + blk] = cnt[b];   // bucket-major
}

// pack = src (17 bits) | dst_local (8 bits) << 17
__global__ __launch_bounds__(256) void k_p2(int2* __restrict__ tmp, const int* __restrict__ obh,
                                            const int* __restrict__ src,
                                            const int* __restrict__ dst,
                                            const float* __restrict__ ew) {
    __shared__ int cur[NB1];
    int t = threadIdx.x, blk = blockIdx.x;
    for (int b = t; b < NB1; b += 256) cur[b] = obh[b * BLK1 + blk];
    __syncthreads();
    int base = blk * EPB;
    for (int i = t; i < EPB; i += 256) {
        int e = base + i;
        int d = dst[e];
        int pos = atomicAdd(&cur[d >> 8], 1);
        tmp[pos] = make_int2(src[e] | ((d & 255) << 17), __float_as_int(ew[e]));
    }
}

__global__ __launch_bounds__(256) void k_p3a(int* __restrict__ deg, float* __restrict__ dinv,
                                             const int2* __restrict__ tmp,
                                             const int* __restrict__ obh) {
    __shared__ int h[NPB];
    __shared__ float ws[NPB];
    int t = threadIdx.x, b = blockIdx.x;
    for (int i = t; i < NPB; i += 256) { h[i] = 0; ws[i] = 0.f; }
    __syncthreads();
    int a  = obh[b * BLK1];
    int e_ = (b == NB1 - 1) ? E1 : obh[(b + 1) * BLK1];
    for (int i = a + t; i < e_; i += 256) {
        int2 ed = tmp[i];
        int dl = (ed.x >> 17) & 255;
        atomicAdd(&h[dl], 1);
        atomicAdd(&ws[dl], __int_as_float(ed.y));
    }
    __syncthreads();
    for (int i = t; i < NPB; i += 256) {
        deg[b * NPB + i] = h[i];
        dinv[b * NPB + i] = rsqrtf(1.f + ws[i]);
    }
}

__global__ __launch_bounds__(256) void k_p3b(int2* __restrict__ edges,
                                             const int2* __restrict__ tmp,
                                             const int* __restrict__ obh,
                                             const int* __restrict__ row,
                                             const float* __restrict__ dinv) {
    __shared__ int cur[NPB];
    __shared__ float dvl[NPB];
    int t = threadIdx.x, b = blockIdx.x;
    int n0 = b * NPB;
    for (int i = t; i < NPB; i += 256) {
        cur[i] = row[n0 + i];
        dvl[i] = dinv[n0 + i];
    }
    __syncthreads();
    int a  = obh[b * BLK1];
    int e_ = (b == NB1 - 1) ? E1 : obh[(b + 1) * BLK1];
    for (int i = a + t; i < e_; i += 256) {
        int2 ed = tmp[i];
        int dl = (ed.x >> 17) & 255;
        int s = ed.x & 0x1FFFF;
        int pos = atomicAdd(&cur[dl], 1);
        float w = dinv[s] * __int_as_float(ed.y) * dvl[dl];
        edges[pos] = make_int2(s, __float_as_int(w));
    }
}

// ---------------- dense ops ----------------

__device__ __forceinline__ float4 ldx(const float* x, size_t idx) {
    return *(const float4*)(x + idx);
}
__device__ __forceinline__ float4 ldx(const __half* x, size_t idx) {
    uint2 u = *(const uint2*)(x + idx);
    __half2 a = *(__half2*)&u.x, b = *(__half2*)&u.y;
    float2 fa = __half22float2(a), fb = __half22float2(b);
    return make_float4(fa.x, fa.y, fb.x, fb.y);
}

// out_f16[n][64] = x[n][K] @ W[K][64], fused over both graphs by block range.
// Block: 256 rows x 64 cols; per-thread 8x8 tile. Output fp16 (halves gather volume).
template <int K, typename T>
__global__ __launch_bounds__(256) void k_gemm(__half* __restrict__ out1, const T* __restrict__ x1,
                                              const float* __restrict__ W1, int n1_,
                                              __half* __restrict__ out2, const T* __restrict__ x2,
                                              const float* __restrict__ W2, int n2_, int split) {
    __shared__ float Wl[32 * 64];       // [kk][col]
    __shared__ float xs[256 * 37];      // [r][kk], stride 37
    int tid = threadIdx.x;
    __half* out; const T* x; const float* W; int n; int row0;
    if ((int)blockIdx.x < split) { out = out1; x = x1; W = W1; n = n1_; row0 = blockIdx.x * 256; }
    else { out = out2; x = x2; W = W2; n = n2_; row0 = (blockIdx.x - split) * 256; }
    int r0 = (tid >> 3) * 8;
    int c0 = (tid & 7) * 8;
    float acc[8][8];
#pragma unroll
    for (int i = 0; i < 8; i++)
#pragma unroll
        for (int j = 0; j < 8; j++) acc[i][j] = 0.f;

    for (int k0 = 0; k0 < K; k0 += 32) {
        __syncthreads();
        {
            const float4* W4 = (const float4*)(W + k0 * 64);
            float4* Wl4 = (float4*)Wl;
#pragma unroll
            for (int i = 0; i < 2; i++) Wl4[tid + i * 256] = W4[tid + i * 256];
        }
#pragma unroll
        for (int i = 0; i < 8; i++) {
            int idx = tid + i * 256;
            int r = idx >> 3, kq = idx & 7;
            float4 v = make_float4(0.f, 0.f, 0.f, 0.f);
            if (row0 + r < n)
                v = ldx(x, (size_t)(row0 + r) * K + k0 + kq * 4);
            xs[r * 37 + kq * 4 + 0] = v.x;
            xs[r * 37 + kq * 4 + 1] = v.y;
            xs[r * 37 + kq * 4 + 2] = v.z;
            xs[r * 37 + kq * 4 + 3] = v.w;
        }
        __syncthreads();
#pragma unroll 2
        for (int kk = 0; kk < 32; kk++) {
            float4 wlo = *(const float4*)(&Wl[kk * 64 + c0]);
            float4 whi = *(const float4*)(&Wl[kk * 64 + c0 + 4]);
            float xf[8];
#pragma unroll
            for (int i = 0; i < 8; i++) xf[i] = xs[(r0 + i) * 37 + kk];
#pragma unroll
            for (int i = 0; i < 8; i++) {
                acc[i][0] += xf[i] * wlo.x; acc[i][1] += xf[i] * wlo.y;
                acc[i][2] += xf[i] * wlo.z; acc[i][3] += xf[i] * wlo.w;
                acc[i][4] += xf[i] * whi.x; acc[i][5] += xf[i] * whi.y;
                acc[i][6] += xf[i] * whi.z; acc[i][7] += xf[i] * whi.w;
            }
        }
    }
#pragma unroll
    for (int i = 0; i < 8; i++) {
        int row = row0 + r0 + i;
        if (row < n) {
            uint4 o;
            o.x = packh2(acc[i][0], acc[i][1]);
            o.y = packh2(acc[i][2], acc[i][3]);
            o.z = packh2(acc[i][4], acc[i][5]);
            o.w = packh2(acc[i][6], acc[i][7]);
            *(uint4*)(out + (size_t)row * 64 + c0) = o;
        }
    }
}

// fused GCN aggregate: wave per dst node, 8 edge-slots x 8 lanes, uint4 (8 fp16)
// per lane -> one wave-load gathers 8 full h-rows (1 KB), 2-deep = 2 KB in flight.
// Tail edges zero-weight-padded (harmless gather of row 0).
__device__ __forceinline__ void conv_core(__half* __restrict__ out, const __half* __restrict__ h,
                                          const int2* __restrict__ edges,
                                          const int* __restrict__ row,
                                          const float* __restrict__ dinv,
                                          const float* __restrict__ bias, int d, int lane) {
    int slot = lane >> 3;         // edge slot 0..7
    int f8 = lane & 7;            // features f8*8 .. f8*8+7
    int a = row[d], b = row[d + 1];
    float ac0[8] = {0.f,0.f,0.f,0.f,0.f,0.f,0.f,0.f};
    float ac1[8] = {0.f,0.f,0.f,0.f,0.f,0.f,0.f,0.f};
    for (int base = a; base < b; base += 64) {
        int m = b - base; if (m > 64) m = 64;
        int sv = 0, wv = 0;       // zero-pad: w=0 kills invalid-slot contributions
        if (base + lane < b) { int2 e = edges[base + lane]; sv = e.x; wv = e.y; }
        for (int j = 0; j < m; j += 16) {
            int   s0 = __shfl(sv, j + slot);
            float w0 = __int_as_float(__shfl(wv, j + slot));
            int   s1 = __shfl(sv, j + 8 + slot);
            float w1 = __int_as_float(__shfl(wv, j + 8 + slot));
            uint4 v0 = *(const uint4*)(h + (size_t)(s0 * HID + f8 * 8));
            uint4 v1 = *(const uint4*)(h + (size_t)(s1 * HID + f8 * 8));
            const __half2* p0 = (const __half2*)&v0;
            const __half2* p1 = (const __half2*)&v1;
#pragma unroll
            for (int k = 0; k < 4; k++) {
                float2 f0 = __half22float2(p0[k]);
                float2 f1 = __half22float2(p1[k]);
                ac0[2*k]   += f0.x * w0; ac0[2*k+1] += f0.y * w0;
                ac1[2*k]   += f1.x * w1; ac1[2*k+1] += f1.y * w1;
            }
        }
    }
    float r[8];
#pragma unroll
    for (int k = 0; k < 8; k++) {
        float v = ac0[k] + ac1[k];
        v += __shfl_xor(v, 8);
        v += __shfl_xor(v, 16);
        v += __shfl_xor(v, 32);
        r[k] = v;
    }
    if (slot == 0) {
        float di = dinv[d];
        float sl = di * di;
        uint4 hv = *(const uint4*)(h + (size_t)(d * HID + f8 * 8));
        const __half2* hp = (const __half2*)&hv;
        float4 b0 = *(const float4*)(bias + f8 * 8);
        float4 b1 = *(const float4*)(bias + f8 * 8 + 4);
        float2 f;
        float o[8];
        f = __half22float2(hp[0]); o[0] = r[0] + f.x * sl + b0.x; o[1] = r[1] + f.y * sl + b0.y;
        f = __half22float2(hp[1]); o[2] = r[2] + f.x * sl + b0.z; o[3] = r[3] + f.y * sl + b0.w;
        f = __half22float2(hp[2]); o[4] = r[4] + f.x * sl + b1.x; o[5] = r[5] + f.y * sl + b1.y;
        f = __half22float2(hp[3]); o[6] = r[6] + f.x * sl + b1.z; o[7] = r[7] + f.y * sl + b1.w;
        uint4 ov;
        ov.x = packh2(fmaxf(o[0], 0.f), fmaxf(o[1], 0.f));
        ov.y = packh2(fmaxf(o[2], 0.f), fmaxf(o[3], 0.f));
        ov.z = packh2(fmaxf(o[4], 0.f), fmaxf(o[5], 0.f));
        ov.w = packh2(fmaxf(o[6], 0.f), fmaxf(o[7], 0.f));
        *(uint4*)(out + (size_t)(d * HID + f8 * 8)) = ov;
    }
}

__global__ __launch_bounds__(256) void k_conv(__half* __restrict__ o1, const __half* __restrict__ h1,
                                              const int2* __restrict__ e1, const int* __restrict__ r1,
                                              const float* __restrict__ dv1, const float* __restrict__ bi1,
                                              int n1_, int nb1_,
                                              __half* __restrict__ o2, const __half* __restrict__ h2,
                                              const int2* __restrict__ e2, const int* __restrict__ r2,
                                              const float* __restrict__ dv2, const float* __restrict__ bi2,
                                              int n2_) {
    int blk = blockIdx.x;
    int lane = threadIdx.x & 63;
    int w = threadIdx.x >> 6;
    if (blk < nb1_) {
        int d = blk * 4 + w;
        if (d < n1_) conv_core(o1, h1, e1, r1, dv1, bi1, d, lane);
    } else {
        int d = (blk - nb1_) * 4 + w;
        if (d < n2_) conv_core(o2, h2, e2, r2, dv2, bi2, d, lane);
    }
}

// segment-mean pool: wave per segment, 8 node-slots x 8 lanes, fp16 rows (128 B)
// gathered as uint4 -> 8 rows per wave-load. Fused over both graphs.
__device__ __forceinline__ void pool_core(float* __restrict__ emb, const __half* __restrict__ h,
                                          const int* __restrict__ nodeid,
                                          const int* __restrict__ segrow, int s, int lane) {
    int slot = lane >> 3;
    int f8 = lane & 7;
    int a = segrow[s], b = segrow[s + 1];
    float ac0[8] = {0.f,0.f,0.f,0.f,0.f,0.f,0.f,0.f};
    float ac1[8] = {0.f,0.f,0.f,0.f,0.f,0.f,0.f,0.f};
    for (int base = a; base < b; base += 64) {
        int m = b - base; if (m > 64) m = 64;
        int nid = -1;
        if (base + lane < b) nid = nodeid[base + lane];
        for (int j = 0; j < m; j += 16) {
            int q0 = __shfl(nid, j + slot);
            int q1 = __shfl(nid, j + 8 + slot);
            if (q0 >= 0) {
                uint4 v = *(const uint4*)(h + (size_t)(q0 * HID + f8 * 8));
                const __half2* p = (const __half2*)&v;
#pragma unroll
                for (int k = 0; k < 4; k++) {
                    float2 f = __half22float2(p[k]);
                    ac0[2*k] += f.x; ac0[2*k+1] += f.y;
                }
            }
            if (q1 >= 0) {
                uint4 v = *(const uint4*)(h + (size_t)(q1 * HID + f8 * 8));
                const __half2* p = (const __half2*)&v;
#pragma unroll
                for (int k = 0; k < 4; k++) {
                    float2 f = __half22float2(p[k]);
                    ac1[2*k] += f.x; ac1[2*k+1] += f.y;
                }
            }
        }
    }
    float r[8];
#pragma unroll
    for (int k = 0; k < 8; k++) {
        float v = ac0[k] + ac1[k];
        v += __shfl_xor(v, 8);
        v += __shfl_xor(v, 16);
        v += __shfl_xor(v, 32);
        r[k] = v;
    }
    if (slot == 0) {
        float inv = 1.0f / fmaxf((float)(b - a), 1.0f);
        float4 lo = make_float4(r[0] * inv, r[1] * inv, r[2] * inv, r[3] * inv);
        float4 hi = make_float4(r[4] * inv, r[5] * inv, r[6] * inv, r[7] * inv);
        *(float4*)(emb + (size_t)s * HID + f8 * 8)     = lo;
        *(float4*)(emb + (size_t)s * HID + f8 * 8 + 4) = hi;
    }
}

__global__ __launch_bounds__(256) void k_pool(float* __restrict__ em1, const __half* __restrict__ h1,
                                              const int* __restrict__ id1, const int* __restrict__ sr1,
                                              int nbs,
                                              float* __restrict__ em2, const __half* __restrict__ h2,
                                              const int* __restrict__ id2, const int* __restrict__ sr2) {
    int blk = blockIdx.x;
    int lane = threadIdx.x & 63;
    int w = threadIdx.x >> 6;
    if (blk < nbs) {
        int s = blk * 4 + w;
        if (s < NSEG) pool_core(em1, h1, id1, sr1, s, lane);
    } else {
        int s = (blk - nbs) * 4 + w;
        if (s < NSEG) pool_core(em2, h2, id2, sr2, s, lane);
    }
}

// ---------------- classifier ----------------

// computes s = emb1 + emb2 inline; ct==0 blocks also persist esum (each element
// of s is loaded by exactly 4 blocks (all ct), so ct==0 covers it exactly once).
__global__ __launch_bounds__(256) void k_cls(float* __restrict__ part_,
                                             const float* __restrict__ e1,
                                             const float* __restrict__ e2,
                                             float* __restrict__ esum,
                                             const float* __restrict__ Wm1) {
    __shared__ float sl[KCC * 16];      // [kk][b]
    int tid = threadIdx.x;
    int kt = blockIdx.x >> 2, ct = blockIdx.x & 3;
    int k0 = kt * KCC;
    bool wr = (ct == 0);
    for (int i = tid; i < KCC * 16; i += 256) {
        int kk = i & (KCC - 1), b = i >> 7;        // coalesced over kk
        int idx = b * SDIM + k0 + kk;
        float v = e1[idx] + e2[idx];
        sl[kk * 16 + b] = v;
        if (wr) esum[idx] = v;
    }
    __syncthreads();
    int c = ct * 256 + tid;
    bool active = c < CLS;
    float acc[16];
#pragma unroll
    for (int b = 0; b < 16; b++) acc[b] = 0.f;
    const float* wp = Wm1 + (size_t)k0 * CLS + c;
#pragma unroll 2
    for (int kk = 0; kk < KCC; kk++) {
        float w = active ? wp[(size_t)kk * CLS] : 0.f;
        float4 s0 = *(const float4*)(&sl[kk * 16 + 0]);
        float4 s1 = *(const float4*)(&sl[kk * 16 + 4]);
        float4 s2 = *(const float4*)(&sl[kk * 16 + 8]);
        float4 s3 = *(const float4*)(&sl[kk * 16 + 12]);
        acc[0]  += s0.x * w; acc[1]  += s0.y * w; acc[2]  += s0.z * w; acc[3]  += s0.w * w;
        acc[4]  += s1.x * w; acc[5]  += s1.y * w; acc[6]  += s1.z * w; acc[7]  += s1.w * w;
        acc[8]  += s2.x * w; acc[9]  += s2.y * w; acc[10] += s2.z * w; acc[11] += s2.w * w;
        acc[12] += s3.x * w; acc[13] += s3.y * w; acc[14] += s3.z * w; acc[15] += s3.w * w;
    }
    float* pp = part_ + (size_t)(kt * CT1 + ct) * 16 * 256;
#pragma unroll
    for (int b = 0; b < 16; b++) pp[b * 256 + tid] = acc[b];
}

// reduce partials + BatchNorm + LeakyReLU in one pass
__global__ void k_credbn(float* __restrict__ hact, const float* __restrict__ part_,
                         const float* __restrict__ bm1, const float* __restrict__ gamma,
                         const float* __restrict__ beta, const float* __restrict__ mean,
                         const float* __restrict__ var) {
    int idx = blockIdx.x * 256 + threadIdx.x;
    if (idx >= BSZ * CLS) return;
    int b = idx / CLS, c = idx % CLS;
    int ct = c >> 8, cl = c & 255;
    float sum = 0.f;
#pragma unroll 2
    for (int kt = 0; kt < KT1; kt++)
        sum += part_[((size_t)(kt * CT1 + ct) * 16 + b) * 256 + cl];
    float t = sum + bm1[c];
    t = gamma[c] * (t - mean[c]) * rsqrtf(var[c] + 1e-5f) + beta[c];
    hact[idx] = t > 0.f ? t : 0.01f * t;
}

// one block per batch row; 128 partials per output
__global__ void k_out(float* __restrict__ outp, const float* __restrict__ hact,
                      const float* __restrict__ Wm2, const float* __restrict__ bm2) {
    int b = blockIdx.x;
    int tid = threadIdx.x;
    int o = tid & 1, part = tid >> 1;   // 2 outputs x 128 partials
    float acc = (part == 0) ? bm2[o] : 0.f;
    for (int k = part; k < CLS; k += 128) acc += hact[b * CLS + k] * Wm2[k * OCH + o];
    unsafeAtomicAdd(&outp[b * OCH + o], acc);
}

extern "C" void kernel_launch(void* const* d_in, const int* in_sizes, int n_in,
                              void* d_out, int out_size, void* d_ws, size_t ws_size,
                              hipStream_t stream) {
    const float* x1  = (const float*)d_in[0];
    const int*   nl  = (const int*)d_in[1];
    const int*   ei1 = (const int*)d_in[2];
    const float* ew1 = (const float*)d_in[3];
    const int*   ba1 = (const int*)d_in[4];
    const float* x2  = (const float*)d_in[5];
    const int*   rl  = (const int*)d_in[6];
    const int*   ei2 = (const int*)d_in[7];
    const float* ew2 = (const float*)d_in[8];
    const int*   ba2 = (const int*)d_in[9];
    const float* W1a = (const float*)d_in[10];
    const float* b1a = (const float*)d_in[11];
    const float* W1b = (const float*)d_in[12];
    const float* b1b = (const float*)d_in[13];
    const float* W2a = (const float*)d_in[14];
    const float* b2a = (const float*)d_in[15];
    const float* W2b = (const float*)d_in[16];
    const float* b2b = (const float*)d_in[17];
    const float* Wm1 = (const float*)d_in[18];
    const float* bm1 = (const float*)d_in[19];
    const float* gam = (const float*)d_in[20];
    const float* bet = (const float*)d_in[21];
    const float* bmn = (const float*)d_in[22];
    const float* bvr = (const float*)d_in[23];
    const float* Wm2 = (const float*)d_in[24];
    const float* bm2 = (const float*)d_in[25];

    float* out  = (float*)d_out;
    float* emb1 = out + 32;               // embedding        (16 x 9472)
    float* emb2 = emb1 + NSEG * HID;      // embedding_roi
    float* esum = emb2 + NSEG * HID;      // embedding + embedding_roi

    // ---- workspace carve ----
    char* p = (char*)d_ws;
    auto carve = [&](size_t nbytes) { char* q = p; p += (nbytes + 255) & ~(size_t)255; return (void*)q; };
    int*    row1    = (int*)   carve((N1 + 1) * 4);
    int2*   edges1  = (int2*)  carve((size_t)E1 * 8);
    float*  dinv1   = (float*) carve(N1 * 4);
    __half* A1h     = (__half*)carve((size_t)N1 * HID * 2);   // fp16 h (gemm out)
    __half* B1h     = (__half*)carve((size_t)N1 * HID * 2);   // fp16 conv out
    int*    nodeid1 = (int*)   carve(N1 * 4);
    int*    segrow1 = (int*)   carve((NSEG + 1) * 4);
    int*    segoff  = (int*)   carve(2 * NSEG * 4);           // [0..NSEG) g1, [NSEG..) g2
    int*    bh      = (int*)   carve((NB1 * BLK1 + 1) * 4);
    int*    obh     = (int*)   carve((NB1 * BLK1 + 1) * 4);
    int*    deg     = (int*)   carve(N1 * 4);
    int*    row2    = (int*)   carve((N2 + 1) * 4);
    int*    off2    = (int*)   carve(N2 * 4);
    int2*   edges2  = (int2*)  carve((size_t)E2 * 8);
    float*  dinv2   = (float*) carve(N2 * 4);
    __half* A2h     = (__half*)carve((size_t)N2 * HID * 2);
    __half* B2h     = (__half*)carve((size_t)N2 * HID * 2);
    int*    nodeid2 = (int*)   carve(N2 * 4);
    int*    segrow2 = (int*)   carve((NSEG + 1) * 4);
    int*    part    = (int*)   carve(256 * 4);
    float*  hact    = (float*) carve(BSZ * CLS * 4);
    int*    segoff1 = segoff;
    int*    segoff2 = segoff + NSEG;
    int2*  tmp1 = (int2*)B1h;   // 16.8 MB aliases B1h (16.8 MB): CSR build done
                                // before conv1's first B1h write
    float* clsp = (float*)B1h;  // 4.85 MB partial slabs alias B1h: dead after pool

    const int* src1 = ei1;
    const int* dst1 = ei1 + E1;
    const int* src2 = ei2;
    const int* dst2 = ei2 + E2;

    hipMemsetAsync(d_out, 0, (size_t)out_size * sizeof(float), stream);

    // ---------------- graph 2 CSR (small) ----------------
    hipMemsetAsync(off2, 0, N2 * 4, stream);
    k_hist_dst<<<(E2 + 255) / 256, 256, 0, stream>>>(off2, dst2, E2);
    k_scan_one<<<1, 256, 0, stream>>>(off2, row2, off2, N2, nullptr, nullptr, nullptr, 0);
    k_fill_edges<<<(E2 + 255) / 256, 256, 0, stream>>>(edges2, off2, src2, dst2, ew2, E2);
    k_deg_dinv<<<(N2 + 255) / 256, 256, 0, stream>>>(dinv2, row2, edges2, N2);
    k_scale<<<(N2 + 255) / 256, 256, 0, stream>>>(edges2, row2, dinv2, N2);

    // ---------------- graph 1 CSR: radix-partition build ----------------
    k_p1<<<BLK1, 256, 0, stream>>>(bh, dst1);
    k_scan1<<<(NB1 * BLK1 + 1023) / 1024, 256, 0, stream>>>(bh, obh, part, NB1 * BLK1);
    k_scan2<<<1, 256, 0, stream>>>(part, (NB1 * BLK1 + 1023) / 1024);
    k_scan3<<<(NB1 * BLK1 + 255) / 256, 256, 0, stream>>>(obh, part, NB1 * BLK1, E1);
    k_p2<<<BLK1, 256, 0, stream>>>(tmp1, obh, src1, dst1, ew1);
    k_p3a<<<NB1, 256, 0, stream>>>(deg, dinv1, tmp1, obh);
    k_scan1<<<(N1 + 1023) / 1024, 256, 0, stream>>>(deg, row1, part, N1);
    k_scan2<<<1, 256, 0, stream>>>(part, (N1 + 1023) / 1024);
    k_scan3<<<(N1 + 255) / 256, 256, 0, stream>>>(row1, part, N1, E1);
    k_p3b<<<NB1, 256, 0, stream>>>(edges1, tmp1, obh, row1, dinv1);

    // ---------------- fused dense pipeline (both graphs per dispatch) ----------------
    k_gemm<INCH, float><<<GB1 + GB2, 256, 0, stream>>>(A1h, x1, W1a, N1, A2h, x2, W2a, N2, GB1);
    k_conv<<<CB1 + CB2, 256, 0, stream>>>(B1h, A1h, edges1, row1, dinv1, b1a, N1, CB1,
                                          B2h, A2h, edges2, row2, dinv2, b2a, N2);
    k_gemm<HID, __half><<<GB1 + GB2, 256, 0, stream>>>(A1h, B1h, W1b, N1, A2h, B2h, W2b, N2, GB1);
    k_conv<<<CB1 + CB2, 256, 0, stream>>>(B1h, A1h, edges1, row1, dinv1, b1b, N1, CB1,
                                          B2h, A2h, edges2, row2, dinv2, b2b, N2);

    // ---------------- segment CSR + pool (both graphs) ----------------
    hipMemsetAsync(segoff, 0, 2 * NSEG * 4, stream);
    k_hist_seg2<<<(N1 + N2 + 255) / 256, 256, 0, stream>>>(segoff1, ba1, nl, N1,
                                                           segoff2, ba2, rl, N2);
    k_scan_one<<<2, 256, 0, stream>>>(segoff1, segrow1, segoff1, NSEG,
                                      segoff2, segrow2, segoff2, NSEG);
    k_fill_seg2<<<(N1 + N2 + 255) / 256, 256, 0, stream>>>(nodeid1, segoff1, ba1, nl, N1,
                                                           nodeid2, segoff2, ba2, rl, N2);
    k_pool<<<PB + PB, 256, 0, stream>>>(emb1, B1h, nodeid1, segrow1, PB,
                                        emb2, B2h, nodeid2, segrow2);
    // B1h dead from here; clsp aliases it

    // ---------------- classifier ----------------
    k_cls<<<KT1 * CT1, 256, 0, stream>>>(clsp, emb1, emb2, esum, Wm1);
    k_credbn<<<(BSZ * CLS + 255) / 256, 256, 0, stream>>>(hact, clsp, bm1, gam, bet, bmn, bvr);
    k_out<<<BSZ, 256, 0, stream>>>(out, hact, Wm2, bm2);
}